// Round 1
// baseline (943.382 us; speedup 1.0000x reference)
//
#include <hip/hip_runtime.h>

// TBE pooled-sum forward.
// weights: [T, E, D] fp32, indices: [T*B*L] int32 (flat, table-major bags),
// offsets: [T*B+1] int32. Output: [B, T*D] fp32 where out[b, t*D+d] = pooled[t*B+b, d].
//
// One wave (64 lanes) per bag; lane l holds float2 covering dims [2l, 2l+1].
// Each gathered row -> one fully-coalesced 512B wave load. L-loop unrolled x4
// with independent accumulators for memory-level parallelism.

constexpr int T = 16;
constexpr int E = 100000;
constexpr int D = 128;
constexpr int BAGS_PER_TABLE = 4096;
constexpr int NUM_BAGS = T * BAGS_PER_TABLE;   // 65536
constexpr int WAVES_PER_BLOCK = 4;             // block = 256 threads

__global__ __launch_bounds__(256) void tbe_pool_kernel(
    const float* __restrict__ weights,
    const int* __restrict__ indices,
    const int* __restrict__ offsets,
    float* __restrict__ out)
{
    const int wave = threadIdx.x >> 6;
    const int lane = threadIdx.x & 63;
    const int bag  = blockIdx.x * WAVES_PER_BLOCK + wave;
    if (bag >= NUM_BAGS) return;

    const int t = bag / BAGS_PER_TABLE;          // table id (bags are table-major)
    const int b = bag - t * BAGS_PER_TABLE;      // bag id within batch

    const int start = offsets[bag];
    const int end   = offsets[bag + 1];

    // Base of this table's rows, viewed as float2 (D/2 = 64 float2 per row).
    const float2* __restrict__ tbl =
        reinterpret_cast<const float2*>(weights + (long long)t * E * D);

    float2 a0 = {0.f, 0.f}, a1 = {0.f, 0.f}, a2 = {0.f, 0.f}, a3 = {0.f, 0.f};

    int i = start;
    for (; i + 4 <= end; i += 4) {
        // Wave-uniform index loads (same address across lanes -> broadcast).
        const int i0 = indices[i];
        const int i1 = indices[i + 1];
        const int i2 = indices[i + 2];
        const int i3 = indices[i + 3];
        // 4 independent 512B gather loads in flight.
        const float2 v0 = tbl[(long long)i0 * (D / 2) + lane];
        const float2 v1 = tbl[(long long)i1 * (D / 2) + lane];
        const float2 v2 = tbl[(long long)i2 * (D / 2) + lane];
        const float2 v3 = tbl[(long long)i3 * (D / 2) + lane];
        a0.x += v0.x; a0.y += v0.y;
        a1.x += v1.x; a1.y += v1.y;
        a2.x += v2.x; a2.y += v2.y;
        a3.x += v3.x; a3.y += v3.y;
    }
    for (; i < end; ++i) {
        const int i0 = indices[i];
        const float2 v0 = tbl[(long long)i0 * (D / 2) + lane];
        a0.x += v0.x; a0.y += v0.y;
    }

    float2 acc;
    acc.x = (a0.x + a1.x) + (a2.x + a3.x);
    acc.y = (a0.y + a1.y) + (a2.y + a3.y);

    // out[b, t*D + 2*lane .. +1] — 512B contiguous per wave, coalesced.
    float2* __restrict__ o =
        reinterpret_cast<float2*>(out + (long long)b * (T * D) + t * D);
    o[lane] = acc;
}

extern "C" void kernel_launch(void* const* d_in, const int* in_sizes, int n_in,
                              void* d_out, int out_size, void* d_ws, size_t ws_size,
                              hipStream_t stream) {
    const float* weights = (const float*)d_in[0];
    const int*   indices = (const int*)d_in[1];
    const int*   offsets = (const int*)d_in[2];
    float*       out     = (float*)d_out;

    const int grid = NUM_BAGS / WAVES_PER_BLOCK;  // 16384 blocks x 256 threads
    tbe_pool_kernel<<<grid, 256, 0, stream>>>(weights, indices, offsets, out);
}